// Round 1
// baseline (1172.850 us; speedup 1.0000x reference)
//
#include <hip/hip_runtime.h>
#include <stdint.h>

#pragma clang fp contract(off)

#define BB 16
#define NCC 80
#define AA 33600
#define TOPK_PRE 750
#define TOPK_POST 30
#define NBINS 16384
#define CAND 1024
#define NW 12  // 750 bits -> 12 u64 words

// ---------------- Kernel A: per-anchor class max + argmax + histogram ----------------
__global__ __launch_bounds__(256) void k_scoremax(const float* __restrict__ raw,
                                                  float* __restrict__ maxs,
                                                  int* __restrict__ clsid,
                                                  unsigned int* __restrict__ hist) {
  int gid = blockIdx.x * blockDim.x + threadIdx.x;
  if (gid >= BB * AA) return;
  int b = gid / AA, a = gid - b * AA;
  const float* p = raw + (size_t)b * 84 * AA + (size_t)4 * AA + a;
  float best = -1e30f; int bc = 0;
  for (int c = 0; c < NCC; ++c) {
    float s = p[(size_t)c * AA];
    if (s > best) { best = s; bc = c; }   // first-max-wins == jnp.argmax
  }
  maxs[gid] = best;
  clsid[gid] = bc;
  int d = 0x3F800000 - (int)__float_as_uint(best);
  if (d < 0) d = 0;
  if (d < NBINS - 1) atomicAdd(&hist[b * NBINS + d], 1u);  // skip far tail: avoids hot-bin atomics
}

// ---------------- Kernel B: per-frame cutoff + compact + sort + box prep ----------------
__global__ __launch_bounds__(256) void k_select(const float* __restrict__ maxs,
                                                const int* __restrict__ clsid,
                                                const unsigned int* __restrict__ hist,
                                                const float* __restrict__ raw,
                                                int* __restrict__ topk,
                                                float* __restrict__ sx1, float* __restrict__ sy1,
                                                float* __restrict__ sx2, float* __restrict__ sy2,
                                                float* __restrict__ sarea) {
  int b = blockIdx.x;
  int tid = threadIdx.x;
  __shared__ unsigned int psum[256];
  __shared__ unsigned int pref[256];
  __shared__ int s_cut;
  __shared__ unsigned int s_cnt;
  __shared__ unsigned int keys[CAND];
  __shared__ float red[256];

  const unsigned int* h = hist + b * NBINS;
  // chunk partial sums (64 bins per thread, L2-resident)
  unsigned int part = 0;
  for (int i = 0; i < 64; ++i) part += h[tid * 64 + i];
  psum[tid] = part;
  if (tid == 0) { s_cut = NBINS - 1; s_cnt = 0; }
  __syncthreads();
  if (tid == 0) {
    unsigned int run = 0;
    for (int t = 0; t < 256; ++t) { pref[t] = run; run += psum[t]; }
  }
  __syncthreads();
  unsigned int base = pref[tid];
  if (base < TOPK_PRE && base + part >= TOPK_PRE) {
    unsigned int run = base;
    for (int i = 0; i < 64; ++i) {
      run += h[tid * 64 + i];
      if (run >= TOPK_PRE) { s_cut = tid * 64 + i; break; }
    }
  }
  for (int i = tid; i < CAND; i += 256) keys[i] = 0xFFFFFFFFu;
  __syncthreads();

  int cut = s_cut;
  for (int a = tid; a < AA; a += 256) {
    float v = maxs[(size_t)b * AA + a];
    int d = 0x3F800000 - (int)__float_as_uint(v);
    if (d >= 0 && d <= cut) {
      unsigned int pos = atomicAdd(&s_cnt, 1u);
      if (pos < CAND) keys[pos] = ((unsigned int)d << 16) | (unsigned int)a;
    }
  }
  __syncthreads();

  // bitonic sort ascending: (d asc, anchor asc) == stable top-k (score desc, idx asc)
  for (int k = 2; k <= CAND; k <<= 1) {
    for (int j = k >> 1; j > 0; j >>= 1) {
      for (int s = tid; s < CAND; s += 256) {
        int p = s ^ j;
        if (p > s) {
          unsigned int x = keys[s], y = keys[p];
          bool up = ((s & k) == 0);
          if ((x > y) == up) { keys[s] = y; keys[p] = x; }
        }
      }
      __syncthreads();
    }
  }

  // gather boxes of top-750, reduce max coord, offset by class, store SoA
  float lx1[3], ly1[3], lx2[3], ly2[3];
  int lcl[3];
  float m = -1e30f;
#pragma unroll
  for (int r = 0; r < 3; ++r) {
    int i = tid + r * 256;
    if (i < TOPK_PRE) {
      int a = (int)(keys[i] & 0xFFFFu);
      topk[b * TOPK_PRE + i] = a;
      const float* p = raw + (size_t)b * 84 * AA + a;
      float x1 = p[0], y1 = p[AA], x2 = p[2 * AA], y2 = p[3 * AA];
      lx1[r] = x1; ly1[r] = y1; lx2[r] = x2; ly2[r] = y2;
      lcl[r] = clsid[(size_t)b * AA + a];
      m = fmaxf(m, fmaxf(fmaxf(x1, y1), fmaxf(x2, y2)));
    }
  }
  red[tid] = m;
  __syncthreads();
  for (int s = 128; s > 0; s >>= 1) {
    if (tid < s) red[tid] = fmaxf(red[tid], red[tid + s]);
    __syncthreads();
  }
  float mc1 = red[0] + 1.0f;  // max_coord + 1.0
#pragma unroll
  for (int r = 0; r < 3; ++r) {
    int i = tid + r * 256;
    if (i < TOPK_PRE) {
      float off = (float)lcl[r] * mc1;
      float X1 = lx1[r] + off, Y1 = ly1[r] + off, X2 = lx2[r] + off, Y2 = ly2[r] + off;
      int o = b * TOPK_PRE + i;
      sx1[o] = X1; sy1[o] = Y1; sx2[o] = X2; sy2[o] = Y2;
      sarea[o] = (X2 - X1) * (Y2 - Y1);  // area from OFFSET coords, as reference does
    }
  }
}

// ---------------- Kernel C: suppression bit-matrix ----------------
__global__ __launch_bounds__(256) void k_iou(const float* __restrict__ sx1, const float* __restrict__ sy1,
                                             const float* __restrict__ sx2, const float* __restrict__ sy2,
                                             const float* __restrict__ sarea,
                                             unsigned long long* __restrict__ mask) {
  int i = blockIdx.x, b = blockIdx.y;
  int base = b * TOPK_PRE;
  float x1i = sx1[base + i], y1i = sy1[base + i];
  float x2i = sx2[base + i], y2i = sy2[base + i];
  float ai = sarea[base + i];
  int tid = threadIdx.x;
#pragma unroll
  for (int it = 0; it < 3; ++it) {
    int j = it * 256 + tid;
    bool sup = false;
    if (j > i && j < TOPK_PRE) {
      float iw = fminf(x2i, sx2[base + j]) - fmaxf(x1i, sx1[base + j]);
      iw = fmaxf(iw, 0.0f);
      float ih = fminf(y2i, sy2[base + j]) - fmaxf(y1i, sy1[base + j]);
      ih = fmaxf(ih, 0.0f);
      float inter = iw * ih;
      float denom = (ai + sarea[base + j]) - inter;  // match (a_i + a_j) - inter order
      sup = (inter / denom) > 0.4f;                  // IEEE div, f32 compare (NumPy2 weak promo)
    }
    unsigned long long bal = __ballot(sup);
    if ((tid & 63) == 0)
      mask[((size_t)(b * TOPK_PRE + i)) * NW + it * 4 + (tid >> 6)] = bal;
  }
}

// ---------------- Kernel D: sequential greedy reduction + stable-partition take-30 ----------------
__global__ __launch_bounds__(64) void k_nmsreduce(const unsigned long long* __restrict__ mask,
                                                  const int* __restrict__ topk,
                                                  int* __restrict__ finalidx) {
  int b = blockIdx.x;
  int lane = threadIdx.x;  // one wave of 64
  unsigned long long kw = ~0ULL;
  const unsigned long long* m = mask + (size_t)b * TOPK_PRE * NW;
  for (int i = 0; i < TOPK_PRE; ++i) {
    unsigned long long cur = __shfl(kw, i >> 6);
    if ((cur >> (i & 63)) & 1ULL) {
      if (lane < NW) kw &= ~m[(size_t)i * NW + lane];
    }
  }
  int cnt = 0;
  for (int i = 0; i < TOPK_PRE && cnt < TOPK_POST; ++i) {
    unsigned long long cur = __shfl(kw, i >> 6);
    if ((cur >> (i & 63)) & 1ULL) {
      if (lane == 0) finalidx[b * TOPK_POST + cnt] = topk[b * TOPK_PRE + i];
      cnt++;
    }
  }
  for (int i = 0; i < TOPK_PRE && cnt < TOPK_POST; ++i) {
    unsigned long long cur = __shfl(kw, i >> 6);
    if (!((cur >> (i & 63)) & 1ULL)) {
      if (lane == 0) finalidx[b * TOPK_POST + cnt] = topk[b * TOPK_PRE + i];
      cnt++;
    }
  }
}

// ---------------- Kernel E: final gather ----------------
__global__ __launch_bounds__(256) void k_gather(const float* __restrict__ vid,
                                                const float* __restrict__ reg,
                                                const float* __restrict__ raw,
                                                const float* __restrict__ maxs,
                                                const int* __restrict__ finalidx,
                                                float* __restrict__ out) {
  int r = blockIdx.x;  // 0..479
  int b = r / TOPK_POST;
  int a = finalidx[r];
  int t = threadIdx.x;
  size_t src = ((size_t)b * AA + a) * 256 + t;
  out[(size_t)r * 256 + t] = vid[src];
  out[122880 + (size_t)r * 256 + t] = reg[src];
  if (t < 4) out[245760 + r * 4 + t] = raw[(size_t)b * 84 * AA + (size_t)t * AA + a];
  if (t == 4) out[247680 + r] = maxs[(size_t)b * AA + a];
}

extern "C" void kernel_launch(void* const* d_in, const int* in_sizes, int n_in,
                              void* d_out, int out_size, void* d_ws, size_t ws_size,
                              hipStream_t stream) {
  const float* raw = (const float*)d_in[0];
  const float* vid = (const float*)d_in[1];
  const float* reg = (const float*)d_in[2];
  float* out = (float*)d_out;

  char* ws = (char*)d_ws;
  size_t off = 0;
  auto alloc = [&](size_t nbytes) -> void* {
    void* p = ws + off;
    off = (off + nbytes + 255) & ~(size_t)255;
    return p;
  };
  float* maxs = (float*)alloc((size_t)BB * AA * 4);
  int* clsid = (int*)alloc((size_t)BB * AA * 4);
  unsigned int* hist = (unsigned int*)alloc((size_t)BB * NBINS * 4);
  int* topk = (int*)alloc((size_t)BB * TOPK_PRE * 4);
  float* sx1 = (float*)alloc((size_t)BB * TOPK_PRE * 4);
  float* sy1 = (float*)alloc((size_t)BB * TOPK_PRE * 4);
  float* sx2 = (float*)alloc((size_t)BB * TOPK_PRE * 4);
  float* sy2 = (float*)alloc((size_t)BB * TOPK_PRE * 4);
  float* sarea = (float*)alloc((size_t)BB * TOPK_PRE * 4);
  unsigned long long* mask = (unsigned long long*)alloc((size_t)BB * TOPK_PRE * NW * 8);
  int* finalidx = (int*)alloc((size_t)BB * TOPK_POST * 4);

  hipMemsetAsync(hist, 0, (size_t)BB * NBINS * 4, stream);

  int total = BB * AA;
  k_scoremax<<<(total + 255) / 256, 256, 0, stream>>>(raw, maxs, clsid, hist);
  k_select<<<BB, 256, 0, stream>>>(maxs, clsid, hist, raw, topk, sx1, sy1, sx2, sy2, sarea);
  k_iou<<<dim3(TOPK_PRE, BB), 256, 0, stream>>>(sx1, sy1, sx2, sy2, sarea, mask);
  k_nmsreduce<<<BB, 64, 0, stream>>>(mask, topk, finalidx);
  k_gather<<<BB * TOPK_POST, 256, 0, stream>>>(vid, reg, raw, maxs, finalidx, out);
}

// Round 2
// 1008.373 us; speedup vs baseline: 1.1631x; 1.1631x over previous
//
#include <hip/hip_runtime.h>
#include <stdint.h>

#pragma clang fp contract(off)

#define BB 16
#define NCC 80
#define AA 33600
#define A4 (AA / 4)
#define TOPK_PRE 750
#define TOPK_POST 30
#define NBINS 16384
#define CAND 1024

// ---------------- Kernel A: per-anchor class max + argmax + histogram (float4) ----------------
__global__ __launch_bounds__(256) void k_scoremax(const float* __restrict__ raw,
                                                  float* __restrict__ maxs,
                                                  int* __restrict__ clsid,
                                                  unsigned int* __restrict__ hist) {
  int gid = blockIdx.x * blockDim.x + threadIdx.x;
  if (gid >= BB * A4) return;
  int b = gid / A4, a4 = (gid - b * A4) * 4;
  const float* p = raw + (size_t)b * 84 * AA + (size_t)4 * AA + a4;
  float4 best = make_float4(-1e30f, -1e30f, -1e30f, -1e30f);
  int bc0 = 0, bc1 = 0, bc2 = 0, bc3 = 0;
  for (int c = 0; c < NCC; ++c) {
    float4 s = *(const float4*)(p + (size_t)c * AA);
    if (s.x > best.x) { best.x = s.x; bc0 = c; }   // first-max-wins == jnp.argmax
    if (s.y > best.y) { best.y = s.y; bc1 = c; }
    if (s.z > best.z) { best.z = s.z; bc2 = c; }
    if (s.w > best.w) { best.w = s.w; bc3 = c; }
  }
  *(float4*)(maxs + (size_t)b * AA + a4) = best;
  *(int4*)(clsid + (size_t)b * AA + a4) = make_int4(bc0, bc1, bc2, bc3);
  unsigned int* h = hist + b * NBINS;
  int d0 = 0x3F800000 - (int)__float_as_uint(best.x);
  int d1 = 0x3F800000 - (int)__float_as_uint(best.y);
  int d2 = 0x3F800000 - (int)__float_as_uint(best.z);
  int d3 = 0x3F800000 - (int)__float_as_uint(best.w);
  if (d0 >= 0 && d0 < NBINS - 1) atomicAdd(&h[d0], 1u);
  if (d1 >= 0 && d1 < NBINS - 1) atomicAdd(&h[d1], 1u);
  if (d2 >= 0 && d2 < NBINS - 1) atomicAdd(&h[d2], 1u);
  if (d3 >= 0 && d3 < NBINS - 1) atomicAdd(&h[d3], 1u);
}

// ---------------- Kernel B: fused cutoff + compact + sort + greedy NMS (early exit) ----------------
__global__ __launch_bounds__(256) void k_selectnms(const float* __restrict__ maxs,
                                                   const int* __restrict__ clsid,
                                                   const unsigned int* __restrict__ hist,
                                                   const float* __restrict__ raw,
                                                   int* __restrict__ finalidx) {
  int b = blockIdx.x;
  int tid = threadIdx.x;
  __shared__ unsigned int psum[256];
  __shared__ unsigned int pref[256];
  __shared__ int s_cut;
  __shared__ unsigned int s_cnt0;
  __shared__ unsigned int keys[CAND];
  __shared__ float red[256];
  __shared__ float bx1[TOPK_PRE], by1[TOPK_PRE], bx2[TOPK_PRE], by2[TOPK_PRE], barea[TOPK_PRE];
  __shared__ int s_keep[TOPK_PRE];
  __shared__ int s_out[TOPK_POST];
  __shared__ int s_cnt;

  // ---- find cutoff bin from histogram ----
  const unsigned int* h = hist + b * NBINS;
  unsigned int part = 0;
  for (int i = 0; i < 64; ++i) part += h[tid * 64 + i];
  psum[tid] = part;
  if (tid == 0) { s_cut = NBINS - 1; s_cnt0 = 0; s_cnt = 0; }
  __syncthreads();
  if (tid == 0) {
    unsigned int run = 0;
    for (int t = 0; t < 256; ++t) { pref[t] = run; run += psum[t]; }
  }
  __syncthreads();
  unsigned int base = pref[tid];
  if (base < TOPK_PRE && base + part >= TOPK_PRE) {
    unsigned int run = base;
    for (int i = 0; i < 64; ++i) {
      run += h[tid * 64 + i];
      if (run >= TOPK_PRE) { s_cut = tid * 64 + i; break; }
    }
  }
  for (int i = tid; i < CAND; i += 256) keys[i] = 0xFFFFFFFFu;
  __syncthreads();

  // ---- compact candidates ----
  int cut = s_cut;
  for (int a = tid; a < AA; a += 256) {
    float v = maxs[(size_t)b * AA + a];
    int d = 0x3F800000 - (int)__float_as_uint(v);
    if (d >= 0 && d <= cut) {
      unsigned int pos = atomicAdd(&s_cnt0, 1u);
      if (pos < CAND) keys[pos] = ((unsigned int)d << 16) | (unsigned int)a;
    }
  }
  __syncthreads();

  // ---- bitonic sort ascending: (d asc, anchor asc) == stable top-k (score desc, idx asc) ----
  for (int k = 2; k <= CAND; k <<= 1) {
    for (int j = k >> 1; j > 0; j >>= 1) {
      for (int s = tid; s < CAND; s += 256) {
        int p = s ^ j;
        if (p > s) {
          unsigned int x = keys[s], y = keys[p];
          bool up = ((s & k) == 0);
          if ((x > y) == up) { keys[s] = y; keys[p] = x; }
        }
      }
      __syncthreads();
    }
  }

  // ---- gather boxes of top-750, reduce max coord, offset by class, stage in LDS ----
  float lx1[3], ly1[3], lx2[3], ly2[3];
  int lcl[3];
  float m = -1e30f;
#pragma unroll
  for (int r = 0; r < 3; ++r) {
    int i = tid + r * 256;
    if (i < TOPK_PRE) {
      int a = (int)(keys[i] & 0xFFFFu);
      const float* p = raw + (size_t)b * 84 * AA + a;
      float x1 = p[0], y1 = p[AA], x2 = p[2 * AA], y2 = p[3 * AA];
      lx1[r] = x1; ly1[r] = y1; lx2[r] = x2; ly2[r] = y2;
      lcl[r] = clsid[(size_t)b * AA + a];
      m = fmaxf(m, fmaxf(fmaxf(x1, y1), fmaxf(x2, y2)));
    }
  }
  red[tid] = m;
  __syncthreads();
  for (int s = 128; s > 0; s >>= 1) {
    if (tid < s) red[tid] = fmaxf(red[tid], red[tid + s]);
    __syncthreads();
  }
  float mc1 = red[0] + 1.0f;  // max_coord + 1.0
#pragma unroll
  for (int r = 0; r < 3; ++r) {
    int i = tid + r * 256;
    if (i < TOPK_PRE) {
      float off = (float)lcl[r] * mc1;
      float X1 = lx1[r] + off, Y1 = ly1[r] + off, X2 = lx2[r] + off, Y2 = ly2[r] + off;
      bx1[i] = X1; by1[i] = Y1; bx2[i] = X2; by2[i] = Y2;
      barea[i] = (X2 - X1) * (Y2 - Y1);  // area from OFFSET coords, as reference does
    }
  }
  for (int i = tid; i < TOPK_PRE; i += 256) s_keep[i] = 1;
  __syncthreads();

  // ---- greedy NMS, on-demand row suppression, early exit at 30 kept ----
  for (int i = 0; i < TOPK_PRE; ++i) {
    if (s_keep[i]) {  // uniform: same LDS word, written only before a prior barrier
      float X1 = bx1[i], Y1 = by1[i], X2 = bx2[i], Y2 = by2[i], Ai = barea[i];
      for (int j = i + 1 + tid; j < TOPK_PRE; j += 256) {
        float iw = fmaxf(fminf(X2, bx2[j]) - fmaxf(X1, bx1[j]), 0.0f);
        float ih = fmaxf(fminf(Y2, by2[j]) - fmaxf(Y1, by1[j]), 0.0f);
        float inter = iw * ih;
        float denom = (Ai + barea[j]) - inter;  // match (a_i + a_j) - inter order
        if (inter / denom > 0.4f) s_keep[j] = 0;  // IEEE div, f32 compare
      }
      if (tid == 0) s_out[s_cnt++] = i;
      __syncthreads();
      if (s_cnt >= TOPK_POST) break;  // exact: first 30 kept == argsort(!keep)[:30] when >=30 kept
    }
  }

  // ---- stable-partition fill (only reachable when loop completed => keep fully computed) ----
  if (tid == 0) {
    int c = s_cnt;
    for (int j = 0; j < TOPK_PRE && c < TOPK_POST; ++j)
      if (!s_keep[j]) s_out[c++] = j;
  }
  __syncthreads();
  if (tid < TOPK_POST) finalidx[b * TOPK_POST + tid] = (int)(keys[s_out[tid]] & 0xFFFFu);
}

// ---------------- Kernel C: final gather ----------------
__global__ __launch_bounds__(256) void k_gather(const float* __restrict__ vid,
                                                const float* __restrict__ reg,
                                                const float* __restrict__ raw,
                                                const float* __restrict__ maxs,
                                                const int* __restrict__ finalidx,
                                                float* __restrict__ out) {
  int r = blockIdx.x;  // 0..479
  int b = r / TOPK_POST;
  int a = finalidx[r];
  int t = threadIdx.x;
  size_t src = ((size_t)b * AA + a) * 256 + t;
  out[(size_t)r * 256 + t] = vid[src];
  out[122880 + (size_t)r * 256 + t] = reg[src];
  if (t < 4) out[245760 + r * 4 + t] = raw[(size_t)b * 84 * AA + (size_t)t * AA + a];
  if (t == 4) out[247680 + r] = maxs[(size_t)b * AA + a];
}

extern "C" void kernel_launch(void* const* d_in, const int* in_sizes, int n_in,
                              void* d_out, int out_size, void* d_ws, size_t ws_size,
                              hipStream_t stream) {
  const float* raw = (const float*)d_in[0];
  const float* vid = (const float*)d_in[1];
  const float* reg = (const float*)d_in[2];
  float* out = (float*)d_out;

  char* ws = (char*)d_ws;
  size_t off = 0;
  auto alloc = [&](size_t nbytes) -> void* {
    void* p = ws + off;
    off = (off + nbytes + 255) & ~(size_t)255;
    return p;
  };
  float* maxs = (float*)alloc((size_t)BB * AA * 4);
  int* clsid = (int*)alloc((size_t)BB * AA * 4);
  unsigned int* hist = (unsigned int*)alloc((size_t)BB * NBINS * 4);
  int* finalidx = (int*)alloc((size_t)BB * TOPK_POST * 4);

  hipMemsetAsync(hist, 0, (size_t)BB * NBINS * 4, stream);

  k_scoremax<<<(BB * A4 + 255) / 256, 256, 0, stream>>>(raw, maxs, clsid, hist);
  k_selectnms<<<BB, 256, 0, stream>>>(maxs, clsid, hist, raw, finalidx);
  k_gather<<<BB * TOPK_POST, 256, 0, stream>>>(vid, reg, raw, maxs, finalidx, out);
}